// Round 6
// baseline (210.080 us; speedup 1.0000x reference)
//
#include <hip/hip_runtime.h>
#include <math.h>

#define DM 2048
#define NEXP 64
#define NTOK 16384
#define NSLICE 4
#define KSL (DM / NSLICE)     // 512 k per K-slice
#define KC 32                 // k per chunk == one MFMA k-step
#define NCH (KSL / KC)        // 16 chunks
#define TPW 32                // tokens per wave (2 M-tiles)
#define MBT 128               // tokens per block (4 waves)
#define NBLK1 ((NTOK / MBT) * NSLICE)  // 512 blocks
#define NKG (DM / KC)                  // 64 global k-steps
#define WFRAG_BYTES (NKG * 12 * 1024)  // [kg][limb*4+nt][lane][16B] = 768 KB
#define PART_BYTES (NSLICE * NEXP * NTOK * 4)  // 16.8 MB, layout [s*64+e][t]

typedef __attribute__((ext_vector_type(8))) short short8;
typedef __attribute__((ext_vector_type(4))) float f32x4;

__device__ __forceinline__ void async16(void* lds, const void* g) {
  __builtin_amdgcn_global_load_lds(
      (const __attribute__((address_space(1))) unsigned int*)g,
      (__attribute__((address_space(3))) unsigned int*)lds, 16, 0, 0);
}

// Truncating 3-limb bf16 split: f = h+m+l, residual ~2^-24 rel.
__device__ __forceinline__ void split3t(float f, unsigned short& h,
                                        unsigned short& m, unsigned short& l) {
  unsigned u = __float_as_uint(f);
  h = (unsigned short)(u >> 16);
  float f1 = f - __uint_as_float(u & 0xFFFF0000u);
  unsigned u1 = __float_as_uint(f1);
  m = (unsigned short)(u1 >> 16);
  float f2 = f1 - __uint_as_float(u1 & 0xFFFF0000u);
  l = (unsigned short)(__float_as_uint(f2) >> 16);
}

__device__ __forceinline__ void split8(const f32x4& a0, const f32x4& a1,
                                       short8& h, short8& m, short8& l) {
  float v[8] = {a0[0], a0[1], a0[2], a0[3], a1[0], a1[1], a1[2], a1[3]};
#pragma unroll
  for (int j = 0; j < 8; ++j) {
    unsigned short hh, mm, ll;
    split3t(v[j], hh, mm, ll);
    h[j] = (short)hh; m[j] = (short)mm; l[j] = (short)ll;
  }
}

// Pre-split W into MFMA-B-fragment-ordered limb blocks (lane-indexed):
// wfrag[((kg*12 + limb*4 + nt)*64 + lane)*8 + j] =
//   limb of W[nt*16 + (lane&15)][kg*32 + (lane>>4)*8 + j]
__global__ void convw_kernel(const float* __restrict__ W,
                             unsigned short* __restrict__ wfrag) {
  const int kg = blockIdx.x;
  const int lane = threadIdx.x & 63;
  const int nt = threadIdx.x >> 6;
  const int e = nt * 16 + (lane & 15);
  const int kpos = kg * 32 + (lane >> 4) * 8;
  const f32x4* wp = (const f32x4*)(W + (size_t)e * DM + kpos);
  f32x4 w0 = wp[0], w1 = wp[1];
  short8 h, m, l;
  split8(w0, w1, h, m, l);
  size_t base = ((size_t)(kg * 12 + nt) * 64 + lane) * 8;
  *(short8*)(wfrag + base) = h;
  *(short8*)(wfrag + base + (size_t)4 * 64 * 8) = m;
  *(short8*)(wfrag + base + (size_t)8 * 64 * 8) = l;
}

// K1: barrier-free, wave-independent bf16x3 MFMA GEMM.
// Wave = 32 tokens x 512 k. A: DMA->wave-private LDS, double-buffered,
// 1-chunk lookahead, manual vmcnt (never drains prefetch). B: direct
// L2 register loads (lane-indexed frag layout). No __syncthreads anywhere.
__global__ __launch_bounds__(256, 2)
void router_gemm(const float* __restrict__ x,
                 const unsigned short* __restrict__ wfrag,
                 float* __restrict__ part) {
  const int lane = threadIdx.x & 63;
  const int wv = threadIdx.x >> 6;
  const int col = lane & 15;
  const int quad = lane >> 4;
  const int tg = blockIdx.x >> 2;     // token group 0..127
  const int s = blockIdx.x & 3;       // K-slice 0..3
  const int tok0 = tg * MBT + wv * TPW;  // wave's 32 tokens

  // wave-private double-buffered x tile: [wave][buf][row 32][k 32]
  __shared__ __align__(16) float xs[4][2][TPW][KC];  // 32 KB

  // DMA addressing: inst i covers rows 8i..8i+7; lane -> (rowoff, unit),
  // global unit XOR-swizzled by rowoff so ds_read_b128 is conflict-free.
  const int rowoff = lane >> 3;
  const int unit = (lane & 7) ^ (rowoff & 7);
  const float* xsrc = x + (size_t)(tok0 + rowoff) * DM + s * KSL + unit * 4;

  auto stage = [&](int buf, int c) {
#pragma unroll
    for (int i = 0; i < 4; ++i)
      async16(&xs[wv][buf][i * 8][0], xsrc + (size_t)(i * 8) * DM + c * KC);
  };

  f32x4 acc[2][4];
#pragma unroll
  for (int mt = 0; mt < 2; ++mt)
#pragma unroll
    for (int nt = 0; nt < 4; ++nt) acc[mt][nt] = (f32x4){0.f, 0.f, 0.f, 0.f};

  const unsigned short* bbase = wfrag + (size_t)(s * NCH) * 12 * 512 +
                                (size_t)lane * 8;

  stage(0, 0);  // prologue: 4 DMAs in flight

  for (int c = 0; c < NCH; ++c) {
    const int cur = c & 1;

    // ---- B limbs for chunk c: 12 register loads (L2-resident wfrag).
    // Issued BEFORE next-stage DMAs so the compiler's B-use wait is
    // vmcnt(4) (keeps prefetch in flight), not vmcnt(0).
    short8 B[3][4];
#pragma unroll
    for (int limb = 0; limb < 3; ++limb)
#pragma unroll
      for (int nt = 0; nt < 4; ++nt)
        B[limb][nt] = *(const short8*)(bbase +
            ((size_t)c * 12 + limb * 4 + nt) * 512);

    asm volatile("" ::: "memory");  // fence: pin B-loads before the DMAs

    if (c + 1 < NCH) {
      stage(cur ^ 1, c + 1);
      // outstanding (old->young): [stage c:4][B:12][stage c+1:4] = 20.
      // vmcnt(16) waits exactly stage c; B + c+1 stay in flight.
      asm volatile("s_waitcnt vmcnt(16)" ::: "memory");
    } else {
      // last chunk: [stage c:4][B:12] -> vmcnt(12) waits stage c.
      asm volatile("s_waitcnt vmcnt(12)" ::: "memory");
    }

    // ---- compute chunk c: 2 M-tiles ----
#pragma unroll
    for (int mt = 0; mt < 2; ++mt) {
      const int row = mt * 16 + col;
      const int u0 = (quad * 2) ^ (col & 7);
      const int u1 = (quad * 2 + 1) ^ (col & 7);
      f32x4 a0 = *(const f32x4*)&xs[wv][cur][row][u0 * 4];
      f32x4 a1 = *(const f32x4*)&xs[wv][cur][row][u1 * 4];
      short8 ah, am, al;
      split8(a0, a1, ah, am, al);
#pragma unroll
      for (int nt = 0; nt < 4; ++nt) {
        f32x4 cc = acc[mt][nt];
        cc = __builtin_amdgcn_mfma_f32_16x16x32_bf16(ah, B[0][nt], cc, 0, 0, 0);
        cc = __builtin_amdgcn_mfma_f32_16x16x32_bf16(ah, B[1][nt], cc, 0, 0, 0);
        cc = __builtin_amdgcn_mfma_f32_16x16x32_bf16(am, B[0][nt], cc, 0, 0, 0);
        cc = __builtin_amdgcn_mfma_f32_16x16x32_bf16(ah, B[2][nt], cc, 0, 0, 0);
        cc = __builtin_amdgcn_mfma_f32_16x16x32_bf16(al, B[0][nt], cc, 0, 0, 0);
        cc = __builtin_amdgcn_mfma_f32_16x16x32_bf16(am, B[1][nt], cc, 0, 0, 0);
        acc[mt][nt] = cc;
      }
    }
    // No barrier: xs is wave-private; chunk c-1's reads were consumed
    // before chunk c's compute, so overwriting buf cur^1 is safe.
  }

  // ---- store partials, layout [s*64+e][t] so reduce reads coalesce.
  // C/D: token = quad*4+r (contiguous r -> f32x4 store), expert = nt*16+col.
#pragma unroll
  for (int mt = 0; mt < 2; ++mt)
#pragma unroll
    for (int nt = 0; nt < 4; ++nt) {
      const size_t e = (size_t)(s * NEXP + nt * 16 + col);
      *(f32x4*)(part + e * NTOK + tok0 + mt * 16 + quad * 4) = acc[mt][nt];
    }
}

// K2: lane-per-token reduce + serial top-2. Quad q sums slice q; shfl_xor
// folds the 4 slices; all lanes of a token column agree; quad 0 writes.
__global__ __launch_bounds__(256, 4)
void router_reduce(const float* __restrict__ part,
                   const float* __restrict__ bias, float* __restrict__ out) {
  const int lane = threadIdx.x & 63;
  const int wv = threadIdx.x >> 6;
  const int q = lane >> 4;
  const int t = blockIdx.x * 64 + wv * 16 + (lane & 15);

  float v1 = -INFINITY, v2 = -INFINITY;
  int i1 = 0, i2 = 0;
#pragma unroll
  for (int e = 0; e < NEXP; ++e) {
    float p = part[(size_t)(q * NEXP + e) * NTOK + t];
    p += __shfl_xor(p, 16, 64);
    p += __shfl_xor(p, 32, 64);
    const float v = p + bias[e];
    const bool a = v > v1;
    const bool b = v > v2;
    const float nv2 = a ? v1 : (b ? v : v2);
    const int ni2 = a ? i1 : (b ? e : i2);
    v2 = nv2; i2 = ni2;
    i1 = a ? e : i1;
    v1 = a ? v : v1;
  }
  if (q == 0) {
    const float ex = expf(v2 - v1);
    const float den = 1.f + ex;
    *(float2*)(out + 2 * t) = make_float2(1.f / den, ex / den);
    *(float2*)(out + 2 * NTOK + 2 * t) = make_float2((float)i1, (float)i2);
  }
}

// Fallback (ws too small): verified single-kernel path, inline W split.
__global__ __launch_bounds__(512, 2)
void router_fb(const float* __restrict__ x, const float* __restrict__ W,
               const float* __restrict__ bias, float* __restrict__ out) {
  const int lane = threadIdx.x & 63;
  const int wv = threadIdx.x >> 6;
  const int col = lane & 15;
  const int quad = lane >> 4;
  const int tok0 = blockIdx.x * 32;
  const int k0 = wv * 256;

  __shared__ float part[8][32][68];

  f32x4 acc[2][4];
#pragma unroll
  for (int ms = 0; ms < 2; ++ms)
#pragma unroll
    for (int nt = 0; nt < 4; ++nt) acc[ms][nt] = (f32x4){0.f, 0.f, 0.f, 0.f};

  for (int ks = 0; ks < 8; ++ks) {
    const int k = k0 + ks * 32 + quad * 8;
    short8 ah[2], am2[2], al2[2];
#pragma unroll
    for (int ms = 0; ms < 2; ++ms) {
      const f32x4* ap = (const f32x4*)(x + (size_t)(tok0 + ms * 16 + col) * DM + k);
      f32x4 a0 = ap[0], a1 = ap[1];
      split8(a0, a1, ah[ms], am2[ms], al2[ms]);
    }
#pragma unroll
    for (int nt = 0; nt < 4; ++nt) {
      short8 bh, bm, bl;
      const f32x4* wp = (const f32x4*)(W + (size_t)(nt * 16 + col) * DM + k);
      f32x4 w0 = wp[0], w1 = wp[1];
      split8(w0, w1, bh, bm, bl);
#pragma unroll
      for (int ms = 0; ms < 2; ++ms) {
        f32x4 cc = acc[ms][nt];
        cc = __builtin_amdgcn_mfma_f32_16x16x32_bf16(ah[ms], bh, cc, 0, 0, 0);
        cc = __builtin_amdgcn_mfma_f32_16x16x32_bf16(ah[ms], bm, cc, 0, 0, 0);
        cc = __builtin_amdgcn_mfma_f32_16x16x32_bf16(am2[ms], bh, cc, 0, 0, 0);
        cc = __builtin_amdgcn_mfma_f32_16x16x32_bf16(ah[ms], bl, cc, 0, 0, 0);
        cc = __builtin_amdgcn_mfma_f32_16x16x32_bf16(al2[ms], bh, cc, 0, 0, 0);
        cc = __builtin_amdgcn_mfma_f32_16x16x32_bf16(am2[ms], bm, cc, 0, 0, 0);
        acc[ms][nt] = cc;
      }
    }
  }
#pragma unroll
  for (int ms = 0; ms < 2; ++ms)
#pragma unroll
    for (int nt = 0; nt < 4; ++nt)
#pragma unroll
      for (int r = 0; r < 4; ++r)
        part[wv][ms * 16 + quad * 4 + r][nt * 16 + col] = acc[ms][nt][r];
  __syncthreads();
  const float bl_ = bias[lane];
#pragma unroll
  for (int ti = 0; ti < 4; ++ti) {
    const int t = wv * 4 + ti;
    float v1 = bl_;
#pragma unroll
    for (int p = 0; p < 8; ++p) v1 += part[p][t][lane];
    int i1 = lane;
    float v2 = -INFINITY;
    int i2 = NEXP;
#pragma unroll
    for (int off = 32; off > 0; off >>= 1) {
      float ov1 = __shfl_xor(v1, off, 64);
      int   oi1 = __shfl_xor(i1, off, 64);
      float ov2 = __shfl_xor(v2, off, 64);
      int   oi2 = __shfl_xor(i2, off, 64);
      bool afirst = (v1 > ov1) || (v1 == ov1 && i1 < oi1);
      float w1v = afirst ? v1 : ov1;  int w1i = afirst ? i1 : oi1;
      float c1v = afirst ? v2 : ov2;  int c1i = afirst ? i2 : oi2;
      float c2v = afirst ? ov1 : v1;  int c2i = afirst ? oi1 : i1;
      bool sfirst = (c1v > c2v) || (c1v == c2v && c1i < c2i);
      v1 = w1v; i1 = w1i;
      v2 = sfirst ? c1v : c2v;
      i2 = sfirst ? c1i : c2i;
    }
    if (lane == 0) {
      const float ex = expf(v2 - v1);
      const float den = 1.f + ex;
      const int token = tok0 + t;
      *(float2*)(out + 2 * token) = make_float2(1.f / den, ex / den);
      *(float2*)(out + 2 * NTOK + 2 * token) =
          make_float2((float)i1, (float)i2);
    }
  }
}

extern "C" void kernel_launch(void* const* d_in, const int* in_sizes, int n_in,
                              void* d_out, int out_size, void* d_ws, size_t ws_size,
                              hipStream_t stream) {
  const float* x = (const float*)d_in[0];
  const float* W = (const float*)d_in[1];
  const float* b = (const float*)d_in[2];
  float* out = (float*)d_out;

  const size_t need = (size_t)WFRAG_BYTES + (size_t)PART_BYTES; // ~17.6 MB
  if (ws_size >= need) {
    unsigned short* wfrag = (unsigned short*)d_ws;
    float* part = (float*)((char*)d_ws + WFRAG_BYTES);
    hipLaunchKernelGGL(convw_kernel, dim3(NKG), dim3(256), 0, stream, W, wfrag);
    hipLaunchKernelGGL(router_gemm, dim3(NBLK1), dim3(256), 0, stream,
                       x, wfrag, part);
    hipLaunchKernelGGL(router_reduce, dim3(NTOK / 64), dim3(256), 0, stream,
                       part, b, out);
  } else {
    hipLaunchKernelGGL(router_fb, dim3(NTOK / 32), dim3(512), 0, stream,
                       x, W, b, out);
  }
}

// Round 7
// 206.882 us; speedup vs baseline: 1.0155x; 1.0155x over previous
//
#include <hip/hip_runtime.h>
#include <math.h>

#define DM 2048
#define NEXP 64
#define NTOK 16384
#define NSLICE 4
#define KSL (DM / NSLICE)     // 512 k per K-slice
#define KC 32                 // k per chunk == one MFMA k-step
#define NCH (KSL / KC)        // 16 chunks
#define MBLK 64               // tokens per block (4 M-tiles of 16)
#define NBLK1 ((NTOK / MBLK) * NSLICE)  // 1024 blocks
#define NKG (DM / KC)                   // 64 global k-steps
#define WFRAG_BYTES (NKG * 12 * 1024)   // [kg][limb*4+nt][lane][16B] = 768 KB
#define PART_BYTES (NSLICE * NEXP * NTOK * 4)  // 16.8 MB, layout [s*64+e][t]

typedef __attribute__((ext_vector_type(8))) short short8;
typedef __attribute__((ext_vector_type(4))) short short4v;
typedef __attribute__((ext_vector_type(4))) float f32x4;

__device__ __forceinline__ void async16(void* lds, const void* g) {
  __builtin_amdgcn_global_load_lds(
      (const __attribute__((address_space(1))) unsigned int*)g,
      (__attribute__((address_space(3))) unsigned int*)lds, 16, 0, 0);
}

// Truncating 3-limb bf16 split: f = h+m+l, residual ~2^-24 rel.
__device__ __forceinline__ void split3t(float f, unsigned short& h,
                                        unsigned short& m, unsigned short& l) {
  unsigned u = __float_as_uint(f);
  h = (unsigned short)(u >> 16);
  float f1 = f - __uint_as_float(u & 0xFFFF0000u);
  unsigned u1 = __float_as_uint(f1);
  m = (unsigned short)(u1 >> 16);
  float f2 = f1 - __uint_as_float(u1 & 0xFFFF0000u);
  l = (unsigned short)(__float_as_uint(f2) >> 16);
}

__device__ __forceinline__ void split8(const f32x4& a0, const f32x4& a1,
                                       short8& h, short8& m, short8& l) {
  float v[8] = {a0[0], a0[1], a0[2], a0[3], a1[0], a1[1], a1[2], a1[3]};
#pragma unroll
  for (int j = 0; j < 8; ++j) {
    unsigned short hh, mm, ll;
    split3t(v[j], hh, mm, ll);
    h[j] = (short)hh; m[j] = (short)mm; l[j] = (short)ll;
  }
}

// Pre-split W into MFMA-B-fragment-ordered limb blocks (lane-indexed):
// wfrag[((kg*12 + limb*4 + nt)*64 + lane)*8 + j] =
//   limb of W[nt*16 + (lane&15)][kg*32 + (lane>>4)*8 + j]
__global__ void convw_kernel(const float* __restrict__ W,
                             unsigned short* __restrict__ wfrag) {
  const int kg = blockIdx.x;
  const int lane = threadIdx.x & 63;
  const int nt = threadIdx.x >> 6;
  const int e = nt * 16 + (lane & 15);
  const int kpos = kg * 32 + (lane >> 4) * 8;
  const f32x4* wp = (const f32x4*)(W + (size_t)e * DM + kpos);
  f32x4 w0 = wp[0], w1 = wp[1];
  short8 h, m, l;
  split8(w0, w1, h, m, l);
  size_t base = ((size_t)(kg * 12 + nt) * 64 + lane) * 8;
  *(short8*)(wfrag + base) = h;
  *(short8*)(wfrag + base + (size_t)4 * 64 * 8) = m;
  *(short8*)(wfrag + base + (size_t)8 * 64 * 8) = l;
}

// K1: N-split waves, shared A-limb LDS, AITER-style non-draining barriers.
// Block = 64 tokens x 64 experts x K-slice 512. Wave w owns experts
// 16w..16w+15 (3 B-loads/chunk). A: DMA fp32 -> LDS, split ONCE to bf16
// limbs in frag-ordered alim, all waves read frags. Prefetch (stage c+1)
// stays in flight across BOTH barriers (vmcnt never drains to 0 mid-loop).
__global__ __launch_bounds__(256, 4)
void router_gemm(const float* __restrict__ x,
                 const unsigned short* __restrict__ wfrag,
                 float* __restrict__ part) {
  const int lane = threadIdx.x & 63;
  const int wv = threadIdx.x >> 6;
  const int col = lane & 15;
  const int quad = lane >> 4;
  const int tg = blockIdx.x >> 2;
  const int s = blockIdx.x & 3;
  const int tok0 = tg * MBLK;

  __shared__ __align__(16) float xs[2][MBLK][KC];             // 16 KB
  __shared__ __align__(16) unsigned short alim[3][4][64][8];  // 12 KB

  // DMA: wave w stages rows 16w..16w+15, 2 insts x 8 rows. lane ->
  // (row 8i+(lane>>3), 16B unit lane&7). LDS dest natural (base+lane*16),
  // so phase-1 readback at the same mapping is linear/conflict-free.
  const float* xsrc =
      x + (size_t)(tok0 + wv * 16 + (lane >> 3)) * DM + s * KSL + (lane & 7) * 4;

  auto stage = [&](int buf, int c) {
#pragma unroll
    for (int i = 0; i < 2; ++i)
      async16(&xs[buf][wv * 16 + i * 8][0], xsrc + (size_t)(i * 8) * DM + c * KC);
  };

  f32x4 acc[4];
#pragma unroll
  for (int mt = 0; mt < 4; ++mt) acc[mt] = (f32x4){0.f, 0.f, 0.f, 0.f};

  const unsigned short* bb = wfrag + (size_t)lane * 8;

  stage(0, 0);  // prologue: 2 DMAs in flight

  for (int c = 0; c < NCH; ++c) {
    const int cur = c & 1;
    const int kg = s * NCH + c;

    // ---- B limbs for wave's N-tile, chunk c: 3 loads (L2) ----
    short8 B0 = *(const short8*)(bb + ((size_t)kg * 12 + 0 + wv) * 512);
    short8 B1 = *(const short8*)(bb + ((size_t)kg * 12 + 4 + wv) * 512);
    short8 B2 = *(const short8*)(bb + ((size_t)kg * 12 + 8 + wv) * 512);
    asm volatile("" ::: "memory");  // pin B-loads before next-stage DMAs

    if (c + 1 < NCH) {
      stage(cur ^ 1, c + 1);
      // outstanding (old->young): [stage c:2][B:3][stage c+1:2] = 7.
      // vmcnt(5) waits exactly stage c; B + prefetch stay in flight.
      asm volatile("s_waitcnt vmcnt(5)\n\ts_barrier" ::: "memory");
    } else {
      // last chunk: [stage c:2][B:3] -> vmcnt(3) waits stage c.
      asm volatile("s_waitcnt vmcnt(3)\n\ts_barrier" ::: "memory");
    }

    // ---- phase 1: split own rows into shared frag-ordered limb LDS ----
#pragma unroll
    for (int i = 0; i < 2; ++i) {
      const int row = wv * 16 + i * 8 + (lane >> 3);
      const int u = lane & 7;  // 16B unit (4 floats) within the row
      f32x4 v = *(const f32x4*)&xs[cur][row][u * 4];
      short4v h, m, l;
#pragma unroll
      for (int j = 0; j < 4; ++j) {
        unsigned short hh, mm, ll;
        split3t(v[j], hh, mm, ll);
        h[j] = (short)hh; m[j] = (short)mm; l[j] = (short)ll;
      }
      // frag slot: consumer lane L holds row m=L&15, k=8*(L>>4)..+7.
      const int slot = (i * 8 + (lane >> 3)) + 16 * (u >> 1);
      const int half = (u & 1) * 4;
      *(short4v*)&alim[0][wv][slot][half] = h;
      *(short4v*)&alim[1][wv][slot][half] = m;
      *(short4v*)&alim[2][wv][slot][half] = l;
    }
    asm volatile("s_waitcnt lgkmcnt(0)\n\ts_barrier" ::: "memory");

    // ---- phase 2: A-frag reads + 6-product MFMA per M-tile ----
#pragma unroll
    for (int mt = 0; mt < 4; ++mt) {
      short8 ah = *(const short8*)&alim[0][mt][lane][0];
      short8 am = *(const short8*)&alim[1][mt][lane][0];
      short8 al = *(const short8*)&alim[2][mt][lane][0];
      f32x4 cc = acc[mt];
      cc = __builtin_amdgcn_mfma_f32_16x16x32_bf16(ah, B0, cc, 0, 0, 0);
      cc = __builtin_amdgcn_mfma_f32_16x16x32_bf16(ah, B1, cc, 0, 0, 0);
      cc = __builtin_amdgcn_mfma_f32_16x16x32_bf16(am, B0, cc, 0, 0, 0);
      cc = __builtin_amdgcn_mfma_f32_16x16x32_bf16(ah, B2, cc, 0, 0, 0);
      cc = __builtin_amdgcn_mfma_f32_16x16x32_bf16(al, B0, cc, 0, 0, 0);
      cc = __builtin_amdgcn_mfma_f32_16x16x32_bf16(am, B1, cc, 0, 0, 0);
      acc[mt] = cc;
    }
    // next iteration's top barrier orders alim overwrite vs these reads
  }

  // ---- store partials [s*64+e][t]: e = wv*16+col, t = quad*4+r ----
#pragma unroll
  for (int mt = 0; mt < 4; ++mt) {
    const size_t e = (size_t)(s * NEXP + wv * 16 + col);
    *(f32x4*)(part + e * NTOK + tok0 + mt * 16 + quad * 4) = acc[mt];
  }
}

// K2: lane-per-token reduce + serial top-2 (verified R6).
__global__ __launch_bounds__(256, 4)
void router_reduce(const float* __restrict__ part,
                   const float* __restrict__ bias, float* __restrict__ out) {
  const int lane = threadIdx.x & 63;
  const int wv = threadIdx.x >> 6;
  const int q = lane >> 4;
  const int t = blockIdx.x * 64 + wv * 16 + (lane & 15);

  float v1 = -INFINITY, v2 = -INFINITY;
  int i1 = 0, i2 = 0;
#pragma unroll
  for (int e = 0; e < NEXP; ++e) {
    float p = part[(size_t)(q * NEXP + e) * NTOK + t];
    p += __shfl_xor(p, 16, 64);
    p += __shfl_xor(p, 32, 64);
    const float v = p + bias[e];
    const bool a = v > v1;
    const bool b = v > v2;
    const float nv2 = a ? v1 : (b ? v : v2);
    const int ni2 = a ? i1 : (b ? e : i2);
    v2 = nv2; i2 = ni2;
    i1 = a ? e : i1;
    v1 = a ? v : v1;
  }
  if (q == 0) {
    const float ex = expf(v2 - v1);
    const float den = 1.f + ex;
    *(float2*)(out + 2 * t) = make_float2(1.f / den, ex / den);
    *(float2*)(out + 2 * NTOK + 2 * t) = make_float2((float)i1, (float)i2);
  }
}

// Fallback (ws too small): verified single-kernel path, inline W split.
__global__ __launch_bounds__(512, 2)
void router_fb(const float* __restrict__ x, const float* __restrict__ W,
               const float* __restrict__ bias, float* __restrict__ out) {
  const int lane = threadIdx.x & 63;
  const int wv = threadIdx.x >> 6;
  const int col = lane & 15;
  const int quad = lane >> 4;
  const int tok0 = blockIdx.x * 32;
  const int k0 = wv * 256;

  __shared__ float part[8][32][68];

  f32x4 acc[2][4];
#pragma unroll
  for (int ms = 0; ms < 2; ++ms)
#pragma unroll
    for (int nt = 0; nt < 4; ++nt) acc[ms][nt] = (f32x4){0.f, 0.f, 0.f, 0.f};

  for (int ks = 0; ks < 8; ++ks) {
    const int k = k0 + ks * 32 + quad * 8;
    short8 ah[2], am2[2], al2[2];
#pragma unroll
    for (int ms = 0; ms < 2; ++ms) {
      const f32x4* ap = (const f32x4*)(x + (size_t)(tok0 + ms * 16 + col) * DM + k);
      f32x4 a0 = ap[0], a1 = ap[1];
      split8(a0, a1, ah[ms], am2[ms], al2[ms]);
    }
#pragma unroll
    for (int nt = 0; nt < 4; ++nt) {
      short8 bh, bm, bl;
      const f32x4* wp = (const f32x4*)(W + (size_t)(nt * 16 + col) * DM + k);
      f32x4 w0 = wp[0], w1 = wp[1];
      split8(w0, w1, bh, bm, bl);
#pragma unroll
      for (int ms = 0; ms < 2; ++ms) {
        f32x4 cc = acc[ms][nt];
        cc = __builtin_amdgcn_mfma_f32_16x16x32_bf16(ah[ms], bh, cc, 0, 0, 0);
        cc = __builtin_amdgcn_mfma_f32_16x16x32_bf16(ah[ms], bm, cc, 0, 0, 0);
        cc = __builtin_amdgcn_mfma_f32_16x16x32_bf16(am2[ms], bh, cc, 0, 0, 0);
        cc = __builtin_amdgcn_mfma_f32_16x16x32_bf16(ah[ms], bl, cc, 0, 0, 0);
        cc = __builtin_amdgcn_mfma_f32_16x16x32_bf16(al2[ms], bh, cc, 0, 0, 0);
        cc = __builtin_amdgcn_mfma_f32_16x16x32_bf16(am2[ms], bm, cc, 0, 0, 0);
        acc[ms][nt] = cc;
      }
    }
  }
#pragma unroll
  for (int ms = 0; ms < 2; ++ms)
#pragma unroll
    for (int nt = 0; nt < 4; ++nt)
#pragma unroll
      for (int r = 0; r < 4; ++r)
        part[wv][ms * 16 + quad * 4 + r][nt * 16 + col] = acc[ms][nt][r];
  __syncthreads();
  const float bl_ = bias[lane];
#pragma unroll
  for (int ti = 0; ti < 4; ++ti) {
    const int t = wv * 4 + ti;
    float v1 = bl_;
#pragma unroll
    for (int p = 0; p < 8; ++p) v1 += part[p][t][lane];
    int i1 = lane;
    float v2 = -INFINITY;
    int i2 = NEXP;
#pragma unroll
    for (int off = 32; off > 0; off >>= 1) {
      float ov1 = __shfl_xor(v1, off, 64);
      int   oi1 = __shfl_xor(i1, off, 64);
      float ov2 = __shfl_xor(v2, off, 64);
      int   oi2 = __shfl_xor(i2, off, 64);
      bool afirst = (v1 > ov1) || (v1 == ov1 && i1 < oi1);
      float w1v = afirst ? v1 : ov1;  int w1i = afirst ? i1 : oi1;
      float c1v = afirst ? v2 : ov2;  int c1i = afirst ? i2 : oi2;
      float c2v = afirst ? ov1 : v1;  int c2i = afirst ? oi1 : i1;
      bool sfirst = (c1v > c2v) || (c1v == c2v && c1i < c2i);
      v1 = w1v; i1 = w1i;
      v2 = sfirst ? c1v : c2v;
      i2 = sfirst ? c1i : c2i;
    }
    if (lane == 0) {
      const float ex = expf(v2 - v1);
      const float den = 1.f + ex;
      const int token = tok0 + t;
      *(float2*)(out + 2 * token) = make_float2(1.f / den, ex / den);
      *(float2*)(out + 2 * NTOK + 2 * token) =
          make_float2((float)i1, (float)i2);
    }
  }
}

extern "C" void kernel_launch(void* const* d_in, const int* in_sizes, int n_in,
                              void* d_out, int out_size, void* d_ws, size_t ws_size,
                              hipStream_t stream) {
  const float* x = (const float*)d_in[0];
  const float* W = (const float*)d_in[1];
  const float* b = (const float*)d_in[2];
  float* out = (float*)d_out;

  const size_t need = (size_t)WFRAG_BYTES + (size_t)PART_BYTES; // ~17.6 MB
  if (ws_size >= need) {
    unsigned short* wfrag = (unsigned short*)d_ws;
    float* part = (float*)((char*)d_ws + WFRAG_BYTES);
    hipLaunchKernelGGL(convw_kernel, dim3(NKG), dim3(256), 0, stream, W, wfrag);
    hipLaunchKernelGGL(router_gemm, dim3(NBLK1), dim3(256), 0, stream,
                       x, wfrag, part);
    hipLaunchKernelGGL(router_reduce, dim3(NTOK / 64), dim3(256), 0, stream,
                       part, b, out);
  } else {
    hipLaunchKernelGGL(router_fb, dim3(NTOK / 32), dim3(512), 0, stream,
                       x, W, b, out);
  }
}